// Round 1
// baseline (347.284 us; speedup 1.0000x reference)
//
#include <hip/hip_runtime.h>
#include <hip/hip_bf16.h>

#define B_ 4
#define S_ 1024
#define D_ 1024
#define H_ 16
#define DH_ 64
#define M_ 4096  // B_*S_

typedef unsigned short u16;
typedef __attribute__((ext_vector_type(4))) float f32x4;
typedef __attribute__((ext_vector_type(8))) short short8;
typedef __attribute__((ext_vector_type(4))) u16 u16x4;

__device__ inline u16 f2bf(float f) {
  union { float f; unsigned u; } v; v.f = f;
  unsigned r = v.u + 0x7FFFu + ((v.u >> 16) & 1u);
  return (u16)(r >> 16);
}

__device__ inline short8 ldfrag(const u16* p) {
  return *reinterpret_cast<const short8*>(p);
}

struct GArgs {
  const void* A[6];
  const float* W[6];
  const float* bias[6];
  void* C[6];
};

// C[M,N] = A[M,K] * W[N,K]^T + bias ; K=N=1024 fixed, M=4096.
// AT: float (convert to bf16 on stage) or u16 (bf16 bits). CT: u16 (bf16) or float.
template<typename AT, typename CT>
__global__ __launch_bounds__(256) void gemm_bt_batched(GArgs args) {
  const int z = blockIdx.z;
  const AT* A = (const AT*)args.A[z];
  const float* W = args.W[z];
  const float* bias = args.bias[z];
  CT* C = (CT*)args.C[z];

  __shared__ u16 Al[128][72];  // [row][k] pad 72: row stride 144B, 16B aligned, ~2-way banks
  __shared__ u16 Bl[128][72];

  const int tid = threadIdx.x;
  const int lane = tid & 63;
  const int wid = tid >> 6;
  const int wr = wid >> 1, wc = wid & 1;     // 2x2 waves, 64x64 each
  const int m0 = blockIdx.y * 128, n0 = blockIdx.x * 128;
  const int l15 = lane & 15, lhi = lane >> 4;

  const f32x4 vzero = {0.f, 0.f, 0.f, 0.f};
  f32x4 acc[4][4];
#pragma unroll
  for (int i = 0; i < 4; ++i)
#pragma unroll
    for (int j = 0; j < 4; ++j) acc[i][j] = vzero;

  for (int kt = 0; kt < 1024; kt += 64) {
    __syncthreads();
    // stage A tile 128x64
#pragma unroll
    for (int i = 0; i < 8; ++i) {
      int g = tid + i * 256;
      int row = g >> 4, col = (g & 15) * 4;
      u16x4 bv;
      if constexpr (sizeof(AT) == 4) {
        float4 vv = *reinterpret_cast<const float4*>((const float*)A + (size_t)(m0 + row) * 1024 + kt + col);
        bv[0] = f2bf(vv.x); bv[1] = f2bf(vv.y); bv[2] = f2bf(vv.z); bv[3] = f2bf(vv.w);
      } else {
        bv = *reinterpret_cast<const u16x4*>((const u16*)A + (size_t)(m0 + row) * 1024 + kt + col);
      }
      *reinterpret_cast<u16x4*>(&Al[row][col]) = bv;
    }
    // stage B tile 128x64 (weights, fp32)
#pragma unroll
    for (int i = 0; i < 8; ++i) {
      int g = tid + i * 256;
      int row = g >> 4, col = (g & 15) * 4;
      float4 vv = *reinterpret_cast<const float4*>(W + (size_t)(n0 + row) * 1024 + kt + col);
      u16x4 bv;
      bv[0] = f2bf(vv.x); bv[1] = f2bf(vv.y); bv[2] = f2bf(vv.z); bv[3] = f2bf(vv.w);
      *reinterpret_cast<u16x4*>(&Bl[row][col]) = bv;
    }
    __syncthreads();

#pragma unroll
    for (int c = 0; c < 2; ++c) {
      short8 af[4], bfr[4];
#pragma unroll
      for (int i = 0; i < 4; ++i) af[i] = ldfrag(&Al[wr * 64 + i * 16 + l15][c * 32 + lhi * 8]);
#pragma unroll
      for (int j = 0; j < 4; ++j) bfr[j] = ldfrag(&Bl[wc * 64 + j * 16 + l15][c * 32 + lhi * 8]);
#pragma unroll
      for (int i = 0; i < 4; ++i)
#pragma unroll
        for (int j = 0; j < 4; ++j)
          acc[i][j] = __builtin_amdgcn_mfma_f32_16x16x32_bf16(af[i], bfr[j], acc[i][j], 0, 0, 0);
    }
  }

  // epilogue: D row=(lane>>4)*4+r, col=lane&15
#pragma unroll
  for (int i = 0; i < 4; ++i) {
#pragma unroll
    for (int j = 0; j < 4; ++j) {
      int col = n0 + wc * 64 + j * 16 + l15;
      float bsv = bias[col];
#pragma unroll
      for (int r = 0; r < 4; ++r) {
        int row = m0 + wr * 64 + i * 16 + lhi * 4 + r;
        float val = acc[i][j][r] + bsv;
        if constexpr (sizeof(CT) == 2) ((u16*)C)[(size_t)row * 1024 + col] = f2bf(val);
        else ((float*)C)[(size_t)row * 1024 + col] = val;
      }
    }
  }
}

// Fused flash attention, bf16 in/out. Block = 4 waves, 64 q-rows (16/wave).
// grid: (S/64, H, 2*B) ; z: path = z>>2, batch = z&3
__global__ __launch_bounds__(256) void attn_fused(const u16* q1b, const u16* k1b, const u16* v1b,
                                                  const u16* q2b, const u16* k2b, const u16* v2b,
                                                  u16* o1, u16* o2) {
  const int qt = blockIdx.x;
  const int h = blockIdx.y;
  const int zb = blockIdx.z;
  const int path = zb >> 2, b = zb & 3;

  const u16* Q = (path == 0) ? q1b : q2b;
  const u16* K = (path == 0) ? k1b : k2b;
  const u16* V = (path == 0) ? v1b : v2b;
  u16* O = (path == 0) ? o1 : o2;

  const size_t base = (size_t)b * S_ * D_ + (size_t)h * DH_;
  const int tid = threadIdx.x;
  const int lane = tid & 63, w = tid >> 6;
  const int l15 = lane & 15, lhi = lane >> 4;

  __shared__ u16 Qs[64][72];
  __shared__ u16 Ks[64][72];
  __shared__ u16 Vt[64][72];      // transposed: Vt[d][key]
  __shared__ u16 Ps[4][16][72];   // per-wave P tile

  // stage Q tile (64 rows x 64 d)
#pragma unroll
  for (int i = 0; i < 4; ++i) {
    int g = tid + i * 256;
    int row = g >> 4, col = (g & 15) * 4;
    *reinterpret_cast<u16x4*>(&Qs[row][col]) =
        *reinterpret_cast<const u16x4*>(Q + base + (size_t)(qt * 64 + row) * D_ + col);
  }
  __syncthreads();
  short8 qa0 = ldfrag(&Qs[w * 16 + l15][lhi * 8]);
  short8 qa1 = ldfrag(&Qs[w * 16 + l15][32 + lhi * 8]);

  const f32x4 vzero = {0.f, 0.f, 0.f, 0.f};
  f32x4 o_acc[4];
#pragma unroll
  for (int dt = 0; dt < 4; ++dt) o_acc[dt] = vzero;
  float m_r[4] = {-1e30f, -1e30f, -1e30f, -1e30f};
  float l_r[4] = {0.f, 0.f, 0.f, 0.f};

  for (int kv = 0; kv < 16; ++kv) {
    __syncthreads();
    // stage K rows and V transposed
#pragma unroll
    for (int i = 0; i < 4; ++i) {
      int g = tid + i * 256;
      int row = g >> 4, col = (g & 15) * 4;
      u16x4 kvv = *reinterpret_cast<const u16x4*>(K + base + (size_t)(kv * 64 + row) * D_ + col);
      *reinterpret_cast<u16x4*>(&Ks[row][col]) = kvv;
      u16x4 vv = *reinterpret_cast<const u16x4*>(V + base + (size_t)(kv * 64 + row) * D_ + col);
      Vt[col + 0][row] = vv[0];
      Vt[col + 1][row] = vv[1];
      Vt[col + 2][row] = vv[2];
      Vt[col + 3][row] = vv[3];
    }
    __syncthreads();

    // QK^T : 4 key-tiles of 16
    f32x4 sf[4];
#pragma unroll
    for (int ktile = 0; ktile < 4; ++ktile) sf[ktile] = vzero;
#pragma unroll
    for (int c = 0; c < 2; ++c) {
      short8 qf = (c == 0) ? qa0 : qa1;
#pragma unroll
      for (int ktile = 0; ktile < 4; ++ktile) {
        short8 kb = ldfrag(&Ks[ktile * 16 + l15][c * 32 + lhi * 8]);
        sf[ktile] = __builtin_amdgcn_mfma_f32_16x16x32_bf16(qf, kb, sf[ktile], 0, 0, 0);
      }
    }

    // scale + online softmax (rows held by 16-lane groups)
    float ps[4][4];
#pragma unroll
    for (int ktile = 0; ktile < 4; ++ktile)
#pragma unroll
      for (int r = 0; r < 4; ++r) ps[ktile][r] = sf[ktile][r] * 0.125f;

#pragma unroll
    for (int r = 0; r < 4; ++r) {
      float pm = fmaxf(fmaxf(ps[0][r], ps[1][r]), fmaxf(ps[2][r], ps[3][r]));
#pragma unroll
      for (int mk = 8; mk >= 1; mk >>= 1) pm = fmaxf(pm, __shfl_xor(pm, mk));
      float mn = fmaxf(m_r[r], pm);
      float sc = __expf(m_r[r] - mn);
      m_r[r] = mn;
      float sum = 0.f;
#pragma unroll
      for (int ktile = 0; ktile < 4; ++ktile) {
        float e = __expf(ps[ktile][r] - mn);
        ps[ktile][r] = e;
        sum += e;
      }
#pragma unroll
      for (int mk = 8; mk >= 1; mk >>= 1) sum += __shfl_xor(sum, mk);
      l_r[r] = l_r[r] * sc + sum;
#pragma unroll
      for (int dt = 0; dt < 4; ++dt) o_acc[dt][r] *= sc;
    }

    // P -> per-wave LDS (transpose through LDS for PV A-operand)
#pragma unroll
    for (int ktile = 0; ktile < 4; ++ktile)
#pragma unroll
      for (int r = 0; r < 4; ++r) Ps[w][lhi * 4 + r][ktile * 16 + l15] = f2bf(ps[ktile][r]);

    // PV
    short8 pa0 = ldfrag(&Ps[w][l15][lhi * 8]);
    short8 pa1 = ldfrag(&Ps[w][l15][32 + lhi * 8]);
#pragma unroll
    for (int dt = 0; dt < 4; ++dt) {
      short8 vb0 = ldfrag(&Vt[dt * 16 + l15][lhi * 8]);
      o_acc[dt] = __builtin_amdgcn_mfma_f32_16x16x32_bf16(pa0, vb0, o_acc[dt], 0, 0, 0);
      short8 vb1 = ldfrag(&Vt[dt * 16 + l15][32 + lhi * 8]);
      o_acc[dt] = __builtin_amdgcn_mfma_f32_16x16x32_bf16(pa1, vb1, o_acc[dt], 0, 0, 0);
    }
  }

  // epilogue
#pragma unroll
  for (int dt = 0; dt < 4; ++dt) {
#pragma unroll
    for (int r = 0; r < 4; ++r) {
      int row = qt * 64 + w * 16 + lhi * 4 + r;
      int col = dt * 16 + l15;
      float val = o_acc[dt][r] / l_r[r];
      O[base + (size_t)row * D_ + col] = f2bf(val);
    }
  }
}

extern "C" void kernel_launch(void* const* d_in, const int* in_sizes, int n_in,
                              void* d_out, int out_size, void* d_ws, size_t ws_size,
                              hipStream_t stream) {
  const float* q   = (const float*)d_in[0];
  const float* k   = (const float*)d_in[1];
  const float* v   = (const float*)d_in[2];
  const float* Wq  = (const float*)d_in[3];  const float* bq  = (const float*)d_in[4];
  const float* Wk  = (const float*)d_in[5];  const float* bk  = (const float*)d_in[6];
  const float* Wv  = (const float*)d_in[7];  const float* bv  = (const float*)d_in[8];
  const float* Wq2 = (const float*)d_in[9];  const float* bq2 = (const float*)d_in[10];
  const float* Wk2 = (const float*)d_in[11]; const float* bk2 = (const float*)d_in[12];
  const float* Wv2 = (const float*)d_in[13]; const float* bv2 = (const float*)d_in[14];
  const float* Wc  = (const float*)d_in[15]; const float* bc  = (const float*)d_in[16];
  const float* Wc2 = (const float*)d_in[17]; const float* bc2 = (const float*)d_in[18];

  u16* ws = (u16*)d_ws;
  const size_t SZ = (size_t)M_ * D_;  // 4M elements
  u16* q1b = ws + 0 * SZ;
  u16* k1b = ws + 1 * SZ;
  u16* v1b = ws + 2 * SZ;
  u16* q2b = ws + 3 * SZ;
  u16* k2b = ws + 4 * SZ;
  u16* v2b = ws + 5 * SZ;
  u16* a1  = ws + 6 * SZ;
  u16* a2  = ws + 7 * SZ;

  // 6 projections: note cross-wiring (q2 from k; k2,v2 from q)
  GArgs pa;
  pa.A[0] = q; pa.W[0] = Wq;  pa.bias[0] = bq;  pa.C[0] = q1b;
  pa.A[1] = k; pa.W[1] = Wk;  pa.bias[1] = bk;  pa.C[1] = k1b;
  pa.A[2] = v; pa.W[2] = Wv;  pa.bias[2] = bv;  pa.C[2] = v1b;
  pa.A[3] = k; pa.W[3] = Wq2; pa.bias[3] = bq2; pa.C[3] = q2b;
  pa.A[4] = q; pa.W[4] = Wk2; pa.bias[4] = bk2; pa.C[4] = k2b;
  pa.A[5] = q; pa.W[5] = Wv2; pa.bias[5] = bv2; pa.C[5] = v2b;
  gemm_bt_batched<float, u16><<<dim3(8, 32, 6), dim3(256), 0, stream>>>(pa);

  attn_fused<<<dim3(16, 16, 8), dim3(256), 0, stream>>>(q1b, k1b, v1b, q2b, k2b, v2b, a1, a2);

  GArgs fa;
  fa.A[0] = a1; fa.W[0] = Wc;  fa.bias[0] = bc;  fa.C[0] = (float*)d_out;
  fa.A[1] = a2; fa.W[1] = Wc2; fa.bias[1] = bc2; fa.C[1] = (float*)d_out + SZ;
  gemm_bt_batched<u16, float><<<dim3(8, 32, 2), dim3(256), 0, stream>>>(fa);
}

// Round 2
// 264.219 us; speedup vs baseline: 1.3144x; 1.3144x over previous
//
#include <hip/hip_runtime.h>
#include <hip/hip_bf16.h>

#define B_ 4
#define S_ 1024
#define D_ 1024
#define H_ 16
#define M_ 4096  // B_*S_

typedef unsigned short u16;
typedef __attribute__((ext_vector_type(4))) float f32x4;
typedef __attribute__((ext_vector_type(8))) short short8;
typedef __attribute__((ext_vector_type(4))) u16 u16x4;

__device__ inline u16 f2bf(float f) {
  return __builtin_bit_cast(u16, __float2bfloat16(f));
}

__device__ inline short8 ldfrag(const u16* p) {
  return *reinterpret_cast<const short8*>(p);
}

struct GArgs {
  const void* A[6];
  const float* W[6];
  const float* bias[6];
  void* C[6];
  float oscale[6];
  int vtrans[6];
};

// C[M,N] = (A[M,K] * W[N,K]^T + bias) * oscale ; K=N=1024, M=4096.
// vtrans: write output as [b][h][d][s] bf16 (for attention V).
template<typename AT, typename CT>
__global__ __launch_bounds__(256) void gemm_bt_batched(GArgs args) {
  const int z = blockIdx.z;
  const AT* A = (const AT*)args.A[z];
  const float* W = args.W[z];
  const float* bias = args.bias[z];
  CT* C = (CT*)args.C[z];
  const float oscale = args.oscale[z];
  const int vtrans = args.vtrans[z];

  __shared__ u16 Al[128][72];
  __shared__ u16 Bl[128][72];

  const int tid = threadIdx.x;
  const int lane = tid & 63;
  const int wid = tid >> 6;
  const int wr = wid >> 1, wc = wid & 1;  // 2x2 waves, 64x64 each
  const int m0 = blockIdx.y * 128, n0 = blockIdx.x * 128;
  const int l15 = lane & 15, lhi = lane >> 4;

  const f32x4 vzero = {0.f, 0.f, 0.f, 0.f};
  f32x4 acc[4][4];
#pragma unroll
  for (int i = 0; i < 4; ++i)
#pragma unroll
    for (int j = 0; j < 4; ++j) acc[i][j] = vzero;

  for (int kt = 0; kt < 1024; kt += 64) {
    __syncthreads();
#pragma unroll
    for (int i = 0; i < 8; ++i) {
      int g = tid + i * 256;
      int row = g >> 4, col = (g & 15) * 4;
      u16x4 bv;
      if constexpr (sizeof(AT) == 4) {
        float4 vv = *reinterpret_cast<const float4*>((const float*)A + (size_t)(m0 + row) * 1024 + kt + col);
        bv[0] = f2bf(vv.x); bv[1] = f2bf(vv.y); bv[2] = f2bf(vv.z); bv[3] = f2bf(vv.w);
      } else {
        bv = *reinterpret_cast<const u16x4*>((const u16*)A + (size_t)(m0 + row) * 1024 + kt + col);
      }
      *reinterpret_cast<u16x4*>(&Al[row][col]) = bv;
    }
#pragma unroll
    for (int i = 0; i < 8; ++i) {
      int g = tid + i * 256;
      int row = g >> 4, col = (g & 15) * 4;
      float4 vv = *reinterpret_cast<const float4*>(W + (size_t)(n0 + row) * 1024 + kt + col);
      u16x4 bv;
      bv[0] = f2bf(vv.x); bv[1] = f2bf(vv.y); bv[2] = f2bf(vv.z); bv[3] = f2bf(vv.w);
      *reinterpret_cast<u16x4*>(&Bl[row][col]) = bv;
    }
    __syncthreads();

#pragma unroll
    for (int c = 0; c < 2; ++c) {
      short8 af[4], bfr[4];
#pragma unroll
      for (int i = 0; i < 4; ++i) af[i] = ldfrag(&Al[wr * 64 + i * 16 + l15][c * 32 + lhi * 8]);
#pragma unroll
      for (int j = 0; j < 4; ++j) bfr[j] = ldfrag(&Bl[wc * 64 + j * 16 + l15][c * 32 + lhi * 8]);
#pragma unroll
      for (int i = 0; i < 4; ++i)
#pragma unroll
        for (int j = 0; j < 4; ++j)
          acc[i][j] = __builtin_amdgcn_mfma_f32_16x16x32_bf16(af[i], bfr[j], acc[i][j], 0, 0, 0);
    }
  }

#pragma unroll
  for (int i = 0; i < 4; ++i) {
#pragma unroll
    for (int j = 0; j < 4; ++j) {
      int n = n0 + wc * 64 + j * 16 + l15;
      float bsv = bias[n];
      int mb = m0 + wr * 64 + i * 16 + lhi * 4;
      if (vtrans) {
        // write bf16 transposed per-head: [b][h][d][s]
        int h = n >> 6, d = n & 63;
        int b = mb >> 10, s0 = mb & 1023;
        u16x4 ov;
#pragma unroll
        for (int r = 0; r < 4; ++r) ov[r] = f2bf((acc[i][j][r] + bsv) * oscale);
        *reinterpret_cast<u16x4*>((u16*)C + ((size_t)((b * 16 + h) * 64 + d)) * 1024 + s0) = ov;
      } else {
#pragma unroll
        for (int r = 0; r < 4; ++r) {
          float val = (acc[i][j][r] + bsv) * oscale;
          if constexpr (sizeof(CT) == 2) ((u16*)C)[(size_t)(mb + r) * 1024 + n] = f2bf(val);
          else ((float*)C)[(size_t)(mb + r) * 1024 + n] = val;
        }
      }
    }
  }
}

// Fused flash attention. 8 waves, 128 q-rows/block (16/wave), KV tile 64.
// Swapped QK^T (S^T in regs, lane=q column); V staged with key-permuted
// columns so S^T C-regs are directly the PV x32 B-operand. No P LDS.
// Q is pre-scaled by 1/8 in the projection. Vt global layout: [b][h][d][s].
__global__ __launch_bounds__(512) void attn_fused(const u16* q1b, const u16* k1b, const u16* vt1,
                                                  const u16* q2b, const u16* k2b, const u16* vt2,
                                                  u16* o1, u16* o2) {
  const int qt = blockIdx.x;
  const int h = blockIdx.y;
  const int zb = blockIdx.z;
  const int path = zb >> 2, b = zb & 3;

  const u16* Q = (path == 0) ? q1b : q2b;
  const u16* K = (path == 0) ? k1b : k2b;
  const u16* V = (path == 0) ? vt1 : vt2;
  u16* O = (path == 0) ? o1 : o2;

  const size_t base_qk = (size_t)b * S_ * D_ + (size_t)h * 64;
  const size_t vbase = (size_t)((b * 16 + h) * 64) * 1024;
  const int tid = threadIdx.x;
  const int lane = tid & 63, w = tid >> 6;
  const int l15 = lane & 15, lhi = lane >> 4;

  __shared__ u16 Ks[64][72];
  __shared__ u16 Vs[64][72];

  // Q fragments direct from global (once per block; L2-resident)
  const int q_row = qt * 128 + w * 16 + l15;
  short8 qa0 = ldfrag(Q + base_qk + (size_t)q_row * 1024 + lhi * 8);
  short8 qa1 = ldfrag(Q + base_qk + (size_t)q_row * 1024 + 32 + lhi * 8);

  const f32x4 vzero = {0.f, 0.f, 0.f, 0.f};
  f32x4 o_acc[4];
#pragma unroll
  for (int dt = 0; dt < 4; ++dt) o_acc[dt] = vzero;
  float m_r = -1e30f, l_r = 0.f;

  for (int kv = 0; kv < 16; ++kv) {
    __syncthreads();
#pragma unroll
    for (int i = 0; i < 2; ++i) {
      int g = tid + i * 512;
      int row = g >> 4;          // 0..63
      int l = g & 15;
      int col = l * 4;
      *reinterpret_cast<u16x4*>(&Ks[row][col]) =
          *reinterpret_cast<const u16x4*>(K + base_qk + (size_t)(kv * 64 + row) * 1024 + col);
      // key-permuted column group: tg = [l3, l1, l0, l2]
      int tg = (l & 8) | ((l & 3) << 1) | ((l >> 2) & 1);
      *reinterpret_cast<u16x4*>(&Vs[row][tg * 4]) =
          *reinterpret_cast<const u16x4*>(V + vbase + (size_t)row * 1024 + kv * 64 + col);
    }
    __syncthreads();

    // S^T = K * Q^T : sf[kt][r] = S^T[key slot kt*16+lhi*4+r][q=l15]
    f32x4 sf[4];
#pragma unroll
    for (int kt = 0; kt < 4; ++kt) sf[kt] = vzero;
#pragma unroll
    for (int c = 0; c < 2; ++c) {
      short8 qf = (c == 0) ? qa0 : qa1;
#pragma unroll
      for (int kt = 0; kt < 4; ++kt) {
        short8 kb = ldfrag(&Ks[kt * 16 + l15][c * 32 + lhi * 8]);
        sf[kt] = __builtin_amdgcn_mfma_f32_16x16x32_bf16(kb, qf, sf[kt], 0, 0, 0);
      }
    }

    // online softmax: per-lane 16 keys, reduce across lhi groups
    float pm = sf[0][0];
#pragma unroll
    for (int kt = 0; kt < 4; ++kt)
#pragma unroll
      for (int r = 0; r < 4; ++r) pm = fmaxf(pm, sf[kt][r]);
    pm = fmaxf(pm, __shfl_xor(pm, 16));
    pm = fmaxf(pm, __shfl_xor(pm, 32));
    float mn = fmaxf(m_r, pm);
    float sc = __expf(m_r - mn);
    m_r = mn;
    float sum = 0.f;
#pragma unroll
    for (int kt = 0; kt < 4; ++kt)
#pragma unroll
      for (int r = 0; r < 4; ++r) {
        float e = __expf(sf[kt][r] - mn);
        sf[kt][r] = e;
        sum += e;
      }
    sum += __shfl_xor(sum, 16);
    sum += __shfl_xor(sum, 32);
    l_r = l_r * sc + sum;
#pragma unroll
    for (int dt = 0; dt < 4; ++dt) o_acc[dt] *= sc;

    // pack P: S^T C-regs are exactly the PV B-frag under the V column perm
    short8 pb0, pb1;
#pragma unroll
    for (int j = 0; j < 4; ++j) {
      pb0[j]     = (short)f2bf(sf[0][j]);
      pb0[4 + j] = (short)f2bf(sf[1][j]);
      pb1[j]     = (short)f2bf(sf[2][j]);
      pb1[4 + j] = (short)f2bf(sf[3][j]);
    }

    // O^T += V^T * P : A = V^T frag (lane=d row), B = P frag (lane=q col)
#pragma unroll
    for (int dt = 0; dt < 4; ++dt) {
      short8 vf0 = ldfrag(&Vs[dt * 16 + l15][lhi * 8]);
      o_acc[dt] = __builtin_amdgcn_mfma_f32_16x16x32_bf16(vf0, pb0, o_acc[dt], 0, 0, 0);
      short8 vf1 = ldfrag(&Vs[dt * 16 + l15][32 + lhi * 8]);
      o_acc[dt] = __builtin_amdgcn_mfma_f32_16x16x32_bf16(vf1, pb1, o_acc[dt], 0, 0, 0);
    }
  }

  // epilogue: lane l15 = q, rows d = dt*16 + lhi*4 + r
  float inv = 1.0f / l_r;
#pragma unroll
  for (int dt = 0; dt < 4; ++dt) {
    u16x4 ov;
#pragma unroll
    for (int r = 0; r < 4; ++r) ov[r] = f2bf(o_acc[dt][r] * inv);
    *reinterpret_cast<u16x4*>(O + base_qk + (size_t)q_row * 1024 + dt * 16 + lhi * 4) = ov;
  }
}

extern "C" void kernel_launch(void* const* d_in, const int* in_sizes, int n_in,
                              void* d_out, int out_size, void* d_ws, size_t ws_size,
                              hipStream_t stream) {
  const float* q   = (const float*)d_in[0];
  const float* k   = (const float*)d_in[1];
  const float* v   = (const float*)d_in[2];
  const float* Wq  = (const float*)d_in[3];  const float* bq  = (const float*)d_in[4];
  const float* Wk  = (const float*)d_in[5];  const float* bk  = (const float*)d_in[6];
  const float* Wv  = (const float*)d_in[7];  const float* bv  = (const float*)d_in[8];
  const float* Wq2 = (const float*)d_in[9];  const float* bq2 = (const float*)d_in[10];
  const float* Wk2 = (const float*)d_in[11]; const float* bk2 = (const float*)d_in[12];
  const float* Wv2 = (const float*)d_in[13]; const float* bv2 = (const float*)d_in[14];
  const float* Wc  = (const float*)d_in[15]; const float* bc  = (const float*)d_in[16];
  const float* Wc2 = (const float*)d_in[17]; const float* bc2 = (const float*)d_in[18];

  u16* ws = (u16*)d_ws;
  const size_t SZ = (size_t)M_ * D_;
  u16* q1b = ws + 0 * SZ;
  u16* k1b = ws + 1 * SZ;
  u16* vt1 = ws + 2 * SZ;   // [b][h][d][s]
  u16* q2b = ws + 3 * SZ;
  u16* k2b = ws + 4 * SZ;
  u16* vt2 = ws + 5 * SZ;   // [b][h][d][s]
  u16* a1  = ws + 6 * SZ;
  u16* a2  = ws + 7 * SZ;

  GArgs pa;
  pa.A[0] = q; pa.W[0] = Wq;  pa.bias[0] = bq;  pa.C[0] = q1b; pa.oscale[0] = 0.125f; pa.vtrans[0] = 0;
  pa.A[1] = k; pa.W[1] = Wk;  pa.bias[1] = bk;  pa.C[1] = k1b; pa.oscale[1] = 1.0f;   pa.vtrans[1] = 0;
  pa.A[2] = v; pa.W[2] = Wv;  pa.bias[2] = bv;  pa.C[2] = vt1; pa.oscale[2] = 1.0f;   pa.vtrans[2] = 1;
  pa.A[3] = k; pa.W[3] = Wq2; pa.bias[3] = bq2; pa.C[3] = q2b; pa.oscale[3] = 0.125f; pa.vtrans[3] = 0;
  pa.A[4] = q; pa.W[4] = Wk2; pa.bias[4] = bk2; pa.C[4] = k2b; pa.oscale[4] = 1.0f;   pa.vtrans[4] = 0;
  pa.A[5] = q; pa.W[5] = Wv2; pa.bias[5] = bv2; pa.C[5] = vt2; pa.oscale[5] = 1.0f;   pa.vtrans[5] = 1;
  gemm_bt_batched<float, u16><<<dim3(8, 32, 6), dim3(256), 0, stream>>>(pa);

  attn_fused<<<dim3(8, 16, 8), dim3(512), 0, stream>>>(q1b, k1b, vt1, q2b, k2b, vt2, a1, a2);

  GArgs fa;
  fa.A[0] = a1; fa.W[0] = Wc;  fa.bias[0] = bc;  fa.C[0] = (float*)d_out;      fa.oscale[0] = 1.0f; fa.vtrans[0] = 0;
  fa.A[1] = a2; fa.W[1] = Wc2; fa.bias[1] = bc2; fa.C[1] = (float*)d_out + SZ; fa.oscale[1] = 1.0f; fa.vtrans[1] = 0;
  gemm_bt_batched<u16, float><<<dim3(8, 32, 2), dim3(256), 0, stream>>>(fa);
}

// Round 3
// 220.191 us; speedup vs baseline: 1.5772x; 1.2000x over previous
//
#include <hip/hip_runtime.h>
#include <hip/hip_bf16.h>

#define B_ 4
#define S_ 1024
#define D_ 1024
#define H_ 16
#define M_ 4096  // B_*S_

typedef unsigned short u16;
typedef __attribute__((ext_vector_type(4))) float f32x4;
typedef __attribute__((ext_vector_type(8))) short short8;
typedef __attribute__((ext_vector_type(4))) u16 u16x4;

__device__ inline u16 f2bf(float f) {
  return __builtin_bit_cast(u16, __float2bfloat16(f));
}

__device__ inline short8 ldfrag(const u16* p) {
  return *reinterpret_cast<const short8*>(p);
}

__device__ inline void gload_lds16(const void* g, void* l) {
  __builtin_amdgcn_global_load_lds((const __attribute__((address_space(1))) void*)g,
                                   (__attribute__((address_space(3))) void*)l,
                                   16, 0, 0);
}

struct GArgs {
  const void* A[6];
  const void* W[6];
  const float* bias[6];
  void* C[6];
  float oscale[6];
  int vtrans[6];
};

// ---------------- fp32 -> bf16 bulk convert ----------------
struct CvtArgs {
  const float* src[11];
  u16* dst[11];
  int n4[11];  // count of float4 groups
};

__global__ __launch_bounds__(256) void cvt_f32_bf16(CvtArgs a) {
  const int z = blockIdx.y;
  const float4* s = (const float4*)a.src[z];
  u16x4* d = (u16x4*)a.dst[z];
  const int n4 = a.n4[z];
  for (int i = blockIdx.x * blockDim.x + threadIdx.x; i < n4; i += gridDim.x * blockDim.x) {
    float4 v = s[i];
    u16x4 o;
    o[0] = f2bf(v.x); o[1] = f2bf(v.y); o[2] = f2bf(v.z); o[3] = f2bf(v.w);
    d[i] = o;
  }
}

// ---------------- bf16 GEMM, m97 structure ----------------
// C[M,N] = (A[M,K] * W[N,K]^T + bias) * oscale ; K=N=1024, M=4096, all bf16 in.
// global_load_lds width-16 staging into linear LDS [128][64]; 2-barrier K-loop.
// Grid fixed (8, 32, z). XCD-bijective swizzle: each XCD gets a 4x8 supertile.
template<typename CT>
__global__ __launch_bounds__(256) void gemm_bt_lds(GArgs args) {
  const int z = blockIdx.z;
  const u16* A = (const u16*)args.A[z];
  const u16* W = (const u16*)args.W[z];
  const float* bias = args.bias[z];
  CT* C = (CT*)args.C[z];
  const float oscale = args.oscale[z];
  const int vtrans = args.vtrans[z];

  __shared__ u16 Al[128 * 64];
  __shared__ u16 Bl[128 * 64];

  const int tid = threadIdx.x;
  const int lane = tid & 63;
  const int w = tid >> 6;                 // 4 waves
  const int wr = w >> 1, wc = w & 1;      // 2x2 waves, 64x64 each
  const int l15 = lane & 15, lhi = lane >> 4;

  // XCD swizzle (grid 8 x 32 per z; 256 blocks; 8 XCDs x 32-block chunks of 4x8)
  const int lin = blockIdx.x + blockIdx.y * 8;
  const int xcd = lin & 7, idx = lin >> 3;
  const int bx = (xcd & 1) * 4 + (idx >> 3);
  const int by = (xcd >> 1) * 8 + (idx & 7);
  const int m0 = by * 128, n0 = bx * 128;

  // per-lane staging offsets (row = lane/8, colu16 = (lane&7)*8 within 8-row block)
  const int srow = lane >> 3;
  const int scol = (lane & 7) * 8;

  const f32x4 vzero = {0.f, 0.f, 0.f, 0.f};
  f32x4 acc[4][4];
#pragma unroll
  for (int i = 0; i < 4; ++i)
#pragma unroll
    for (int j = 0; j < 4; ++j) acc[i][j] = vzero;

  for (int kt = 0; kt < 1024; kt += 64) {
    __syncthreads();  // prior compute done before overwrite
    const u16* Ag = A + (size_t)m0 * 1024 + kt;
    const u16* Wg = W + (size_t)n0 * 1024 + kt;
#pragma unroll
    for (int j = 0; j < 4; ++j) {
      int rb = w * 32 + j * 8;  // 8-row block this wave-issue covers
      gload_lds16(Ag + (size_t)(rb + srow) * 1024 + scol, &Al[rb * 64]);
      gload_lds16(Wg + (size_t)(rb + srow) * 1024 + scol, &Bl[rb * 64]);
    }
    __syncthreads();  // vmcnt(0) drained: tiles ready

#pragma unroll
    for (int c = 0; c < 2; ++c) {
      short8 af[4], bfr[4];
#pragma unroll
      for (int i = 0; i < 4; ++i) af[i] = ldfrag(&Al[(wr * 64 + i * 16 + l15) * 64 + c * 32 + lhi * 8]);
#pragma unroll
      for (int j = 0; j < 4; ++j) bfr[j] = ldfrag(&Bl[(wc * 64 + j * 16 + l15) * 64 + c * 32 + lhi * 8]);
#pragma unroll
      for (int i = 0; i < 4; ++i)
#pragma unroll
        for (int j = 0; j < 4; ++j)
          acc[i][j] = __builtin_amdgcn_mfma_f32_16x16x32_bf16(af[i], bfr[j], acc[i][j], 0, 0, 0);
    }
  }

#pragma unroll
  for (int i = 0; i < 4; ++i) {
#pragma unroll
    for (int j = 0; j < 4; ++j) {
      int n = n0 + wc * 64 + j * 16 + l15;
      float bsv = bias[n];
      int mb = m0 + wr * 64 + i * 16 + lhi * 4;
      if (vtrans) {
        int h = n >> 6, d = n & 63;
        int b = mb >> 10, s0 = mb & 1023;
        u16x4 ov;
#pragma unroll
        for (int r = 0; r < 4; ++r) ov[r] = f2bf((acc[i][j][r] + bsv) * oscale);
        *reinterpret_cast<u16x4*>((u16*)C + ((size_t)((b * 16 + h) * 64 + d)) * 1024 + s0) = ov;
      } else {
#pragma unroll
        for (int r = 0; r < 4; ++r) {
          float val = (acc[i][j][r] + bsv) * oscale;
          if constexpr (sizeof(CT) == 2) ((u16*)C)[(size_t)(mb + r) * 1024 + n] = f2bf(val);
          else ((float*)C)[(size_t)(mb + r) * 1024 + n] = val;
        }
      }
    }
  }
}

// ---------------- fallback reg-staged GEMM (fp32/bf16 A) ----------------
template<typename AT, typename CT>
__global__ __launch_bounds__(256) void gemm_bt_batched(GArgs args) {
  const int z = blockIdx.z;
  const AT* A = (const AT*)args.A[z];
  const float* W = (const float*)args.W[z];
  const float* bias = args.bias[z];
  CT* C = (CT*)args.C[z];
  const float oscale = args.oscale[z];
  const int vtrans = args.vtrans[z];

  __shared__ u16 Al[128][72];
  __shared__ u16 Bl[128][72];

  const int tid = threadIdx.x;
  const int lane = tid & 63;
  const int wid = tid >> 6;
  const int wr = wid >> 1, wc = wid & 1;
  const int m0 = blockIdx.y * 128, n0 = blockIdx.x * 128;
  const int l15 = lane & 15, lhi = lane >> 4;

  const f32x4 vzero = {0.f, 0.f, 0.f, 0.f};
  f32x4 acc[4][4];
#pragma unroll
  for (int i = 0; i < 4; ++i)
#pragma unroll
    for (int j = 0; j < 4; ++j) acc[i][j] = vzero;

  for (int kt = 0; kt < 1024; kt += 64) {
    __syncthreads();
#pragma unroll
    for (int i = 0; i < 8; ++i) {
      int g = tid + i * 256;
      int row = g >> 4, col = (g & 15) * 4;
      u16x4 bv;
      if constexpr (sizeof(AT) == 4) {
        float4 vv = *reinterpret_cast<const float4*>((const float*)A + (size_t)(m0 + row) * 1024 + kt + col);
        bv[0] = f2bf(vv.x); bv[1] = f2bf(vv.y); bv[2] = f2bf(vv.z); bv[3] = f2bf(vv.w);
      } else {
        bv = *reinterpret_cast<const u16x4*>((const u16*)A + (size_t)(m0 + row) * 1024 + kt + col);
      }
      *reinterpret_cast<u16x4*>(&Al[row][col]) = bv;
    }
#pragma unroll
    for (int i = 0; i < 8; ++i) {
      int g = tid + i * 256;
      int row = g >> 4, col = (g & 15) * 4;
      float4 vv = *reinterpret_cast<const float4*>((const float*)W + (size_t)(n0 + row) * 1024 + kt + col);
      u16x4 bv;
      bv[0] = f2bf(vv.x); bv[1] = f2bf(vv.y); bv[2] = f2bf(vv.z); bv[3] = f2bf(vv.w);
      *reinterpret_cast<u16x4*>(&Bl[row][col]) = bv;
    }
    __syncthreads();

#pragma unroll
    for (int c = 0; c < 2; ++c) {
      short8 af[4], bfr[4];
#pragma unroll
      for (int i = 0; i < 4; ++i) af[i] = ldfrag(&Al[wr * 64 + i * 16 + l15][c * 32 + lhi * 8]);
#pragma unroll
      for (int j = 0; j < 4; ++j) bfr[j] = ldfrag(&Bl[wc * 64 + j * 16 + l15][c * 32 + lhi * 8]);
#pragma unroll
      for (int i = 0; i < 4; ++i)
#pragma unroll
        for (int j = 0; j < 4; ++j)
          acc[i][j] = __builtin_amdgcn_mfma_f32_16x16x32_bf16(af[i], bfr[j], acc[i][j], 0, 0, 0);
    }
  }

#pragma unroll
  for (int i = 0; i < 4; ++i) {
#pragma unroll
    for (int j = 0; j < 4; ++j) {
      int n = n0 + wc * 64 + j * 16 + l15;
      float bsv = bias[n];
      int mb = m0 + wr * 64 + i * 16 + lhi * 4;
      if (vtrans) {
        int h = n >> 6, d = n & 63;
        int b = mb >> 10, s0 = mb & 1023;
        u16x4 ov;
#pragma unroll
        for (int r = 0; r < 4; ++r) ov[r] = f2bf((acc[i][j][r] + bsv) * oscale);
        *reinterpret_cast<u16x4*>((u16*)C + ((size_t)((b * 16 + h) * 64 + d)) * 1024 + s0) = ov;
      } else {
#pragma unroll
        for (int r = 0; r < 4; ++r) {
          float val = (acc[i][j][r] + bsv) * oscale;
          if constexpr (sizeof(CT) == 2) ((u16*)C)[(size_t)(mb + r) * 1024 + n] = f2bf(val);
          else ((float*)C)[(size_t)(mb + r) * 1024 + n] = val;
        }
      }
    }
  }
}

// ---------------- fused flash attention (unchanged from round 2) ----------------
__global__ __launch_bounds__(512) void attn_fused(const u16* q1b, const u16* k1b, const u16* vt1,
                                                  const u16* q2b, const u16* k2b, const u16* vt2,
                                                  u16* o1, u16* o2) {
  const int qt = blockIdx.x;
  const int h = blockIdx.y;
  const int zb = blockIdx.z;
  const int path = zb >> 2, b = zb & 3;

  const u16* Q = (path == 0) ? q1b : q2b;
  const u16* K = (path == 0) ? k1b : k2b;
  const u16* V = (path == 0) ? vt1 : vt2;
  u16* O = (path == 0) ? o1 : o2;

  const size_t base_qk = (size_t)b * S_ * D_ + (size_t)h * 64;
  const size_t vbase = (size_t)((b * 16 + h) * 64) * 1024;
  const int tid = threadIdx.x;
  const int lane = tid & 63, w = tid >> 6;
  const int l15 = lane & 15, lhi = lane >> 4;

  __shared__ u16 Ks[64][72];
  __shared__ u16 Vs[64][72];

  const int q_row = qt * 128 + w * 16 + l15;
  short8 qa0 = ldfrag(Q + base_qk + (size_t)q_row * 1024 + lhi * 8);
  short8 qa1 = ldfrag(Q + base_qk + (size_t)q_row * 1024 + 32 + lhi * 8);

  const f32x4 vzero = {0.f, 0.f, 0.f, 0.f};
  f32x4 o_acc[4];
#pragma unroll
  for (int dt = 0; dt < 4; ++dt) o_acc[dt] = vzero;
  float m_r = -1e30f, l_r = 0.f;

  for (int kv = 0; kv < 16; ++kv) {
    __syncthreads();
#pragma unroll
    for (int i = 0; i < 2; ++i) {
      int g = tid + i * 512;
      int row = g >> 4;
      int l = g & 15;
      int col = l * 4;
      *reinterpret_cast<u16x4*>(&Ks[row][col]) =
          *reinterpret_cast<const u16x4*>(K + base_qk + (size_t)(kv * 64 + row) * 1024 + col);
      int tg = (l & 8) | ((l & 3) << 1) | ((l >> 2) & 1);
      *reinterpret_cast<u16x4*>(&Vs[row][tg * 4]) =
          *reinterpret_cast<const u16x4*>(V + vbase + (size_t)row * 1024 + kv * 64 + col);
    }
    __syncthreads();

    f32x4 sf[4];
#pragma unroll
    for (int kt = 0; kt < 4; ++kt) sf[kt] = vzero;
#pragma unroll
    for (int c = 0; c < 2; ++c) {
      short8 qf = (c == 0) ? qa0 : qa1;
#pragma unroll
      for (int kt = 0; kt < 4; ++kt) {
        short8 kb = ldfrag(&Ks[kt * 16 + l15][c * 32 + lhi * 8]);
        sf[kt] = __builtin_amdgcn_mfma_f32_16x16x32_bf16(kb, qf, sf[kt], 0, 0, 0);
      }
    }

    float pm = sf[0][0];
#pragma unroll
    for (int kt = 0; kt < 4; ++kt)
#pragma unroll
      for (int r = 0; r < 4; ++r) pm = fmaxf(pm, sf[kt][r]);
    pm = fmaxf(pm, __shfl_xor(pm, 16));
    pm = fmaxf(pm, __shfl_xor(pm, 32));
    float mn = fmaxf(m_r, pm);
    float sc = __expf(m_r - mn);
    m_r = mn;
    float sum = 0.f;
#pragma unroll
    for (int kt = 0; kt < 4; ++kt)
#pragma unroll
      for (int r = 0; r < 4; ++r) {
        float e = __expf(sf[kt][r] - mn);
        sf[kt][r] = e;
        sum += e;
      }
    sum += __shfl_xor(sum, 16);
    sum += __shfl_xor(sum, 32);
    l_r = l_r * sc + sum;
#pragma unroll
    for (int dt = 0; dt < 4; ++dt) o_acc[dt] *= sc;

    short8 pb0, pb1;
#pragma unroll
    for (int j = 0; j < 4; ++j) {
      pb0[j]     = (short)f2bf(sf[0][j]);
      pb0[4 + j] = (short)f2bf(sf[1][j]);
      pb1[j]     = (short)f2bf(sf[2][j]);
      pb1[4 + j] = (short)f2bf(sf[3][j]);
    }

#pragma unroll
    for (int dt = 0; dt < 4; ++dt) {
      short8 vf0 = ldfrag(&Vs[dt * 16 + l15][lhi * 8]);
      o_acc[dt] = __builtin_amdgcn_mfma_f32_16x16x32_bf16(vf0, pb0, o_acc[dt], 0, 0, 0);
      short8 vf1 = ldfrag(&Vs[dt * 16 + l15][32 + lhi * 8]);
      o_acc[dt] = __builtin_amdgcn_mfma_f32_16x16x32_bf16(vf1, pb1, o_acc[dt], 0, 0, 0);
    }
  }

  float inv = 1.0f / l_r;
#pragma unroll
  for (int dt = 0; dt < 4; ++dt) {
    u16x4 ov;
#pragma unroll
    for (int r = 0; r < 4; ++r) ov[r] = f2bf(o_acc[dt][r] * inv);
    *reinterpret_cast<u16x4*>(O + base_qk + (size_t)q_row * 1024 + dt * 16 + lhi * 4) = ov;
  }
}

extern "C" void kernel_launch(void* const* d_in, const int* in_sizes, int n_in,
                              void* d_out, int out_size, void* d_ws, size_t ws_size,
                              hipStream_t stream) {
  const float* q   = (const float*)d_in[0];
  const float* k   = (const float*)d_in[1];
  const float* v   = (const float*)d_in[2];
  const float* Wq  = (const float*)d_in[3];  const float* bq  = (const float*)d_in[4];
  const float* Wk  = (const float*)d_in[5];  const float* bk  = (const float*)d_in[6];
  const float* Wv  = (const float*)d_in[7];  const float* bv  = (const float*)d_in[8];
  const float* Wq2 = (const float*)d_in[9];  const float* bq2 = (const float*)d_in[10];
  const float* Wk2 = (const float*)d_in[11]; const float* bk2 = (const float*)d_in[12];
  const float* Wv2 = (const float*)d_in[13]; const float* bv2 = (const float*)d_in[14];
  const float* Wc  = (const float*)d_in[15]; const float* bc  = (const float*)d_in[16];
  const float* Wc2 = (const float*)d_in[17]; const float* bc2 = (const float*)d_in[18];

  u16* ws = (u16*)d_ws;
  const size_t SZ = (size_t)M_ * D_;      // 4M elements
  const size_t WSZ = (size_t)D_ * D_;     // 1M elements
  u16* q1b = ws + 0 * SZ;
  u16* k1b = ws + 1 * SZ;
  u16* vt1 = ws + 2 * SZ;   // [b][h][d][s]
  u16* q2b = ws + 3 * SZ;
  u16* k2b = ws + 4 * SZ;
  u16* vt2 = ws + 5 * SZ;   // [b][h][d][s]
  u16* a1  = ws + 6 * SZ;
  u16* a2  = ws + 7 * SZ;

  const size_t need = (11 * SZ + 8 * WSZ) * sizeof(u16);  // 100 MB

  if (ws_size >= need) {
    u16* qb = ws + 8 * SZ;
    u16* kb = ws + 9 * SZ;
    u16* vb = ws + 10 * SZ;
    u16* wbase = ws + 11 * SZ;
    u16* WqB  = wbase + 0 * WSZ;
    u16* WkB  = wbase + 1 * WSZ;
    u16* WvB  = wbase + 2 * WSZ;
    u16* Wq2B = wbase + 3 * WSZ;
    u16* Wk2B = wbase + 4 * WSZ;
    u16* Wv2B = wbase + 5 * WSZ;
    u16* WcB  = wbase + 6 * WSZ;
    u16* Wc2B = wbase + 7 * WSZ;

    CvtArgs ca;
    ca.src[0] = q;   ca.dst[0] = qb;   ca.n4[0] = (int)(SZ / 4);
    ca.src[1] = k;   ca.dst[1] = kb;   ca.n4[1] = (int)(SZ / 4);
    ca.src[2] = v;   ca.dst[2] = vb;   ca.n4[2] = (int)(SZ / 4);
    ca.src[3] = Wq;  ca.dst[3] = WqB;  ca.n4[3] = (int)(WSZ / 4);
    ca.src[4] = Wk;  ca.dst[4] = WkB;  ca.n4[4] = (int)(WSZ / 4);
    ca.src[5] = Wv;  ca.dst[5] = WvB;  ca.n4[5] = (int)(WSZ / 4);
    ca.src[6] = Wq2; ca.dst[6] = Wq2B; ca.n4[6] = (int)(WSZ / 4);
    ca.src[7] = Wk2; ca.dst[7] = Wk2B; ca.n4[7] = (int)(WSZ / 4);
    ca.src[8] = Wv2; ca.dst[8] = Wv2B; ca.n4[8] = (int)(WSZ / 4);
    ca.src[9] = Wc;  ca.dst[9] = WcB;  ca.n4[9] = (int)(WSZ / 4);
    ca.src[10] = Wc2; ca.dst[10] = Wc2B; ca.n4[10] = (int)(WSZ / 4);
    cvt_f32_bf16<<<dim3(512, 11), dim3(256), 0, stream>>>(ca);

    GArgs pa;
    pa.A[0] = qb; pa.W[0] = WqB;  pa.bias[0] = bq;  pa.C[0] = q1b; pa.oscale[0] = 0.125f; pa.vtrans[0] = 0;
    pa.A[1] = kb; pa.W[1] = WkB;  pa.bias[1] = bk;  pa.C[1] = k1b; pa.oscale[1] = 1.0f;   pa.vtrans[1] = 0;
    pa.A[2] = vb; pa.W[2] = WvB;  pa.bias[2] = bv;  pa.C[2] = vt1; pa.oscale[2] = 1.0f;   pa.vtrans[2] = 1;
    pa.A[3] = kb; pa.W[3] = Wq2B; pa.bias[3] = bq2; pa.C[3] = q2b; pa.oscale[3] = 0.125f; pa.vtrans[3] = 0;
    pa.A[4] = qb; pa.W[4] = Wk2B; pa.bias[4] = bk2; pa.C[4] = k2b; pa.oscale[4] = 1.0f;   pa.vtrans[4] = 0;
    pa.A[5] = qb; pa.W[5] = Wv2B; pa.bias[5] = bv2; pa.C[5] = vt2; pa.oscale[5] = 1.0f;   pa.vtrans[5] = 1;
    gemm_bt_lds<u16><<<dim3(8, 32, 6), dim3(256), 0, stream>>>(pa);

    attn_fused<<<dim3(8, 16, 8), dim3(512), 0, stream>>>(q1b, k1b, vt1, q2b, k2b, vt2, a1, a2);

    GArgs fa;
    fa.A[0] = a1; fa.W[0] = WcB;  fa.bias[0] = bc;  fa.C[0] = (float*)d_out;      fa.oscale[0] = 1.0f; fa.vtrans[0] = 0;
    fa.A[1] = a2; fa.W[1] = Wc2B; fa.bias[1] = bc2; fa.C[1] = (float*)d_out + SZ; fa.oscale[1] = 1.0f; fa.vtrans[1] = 0;
    gemm_bt_lds<float><<<dim3(8, 32, 2), dim3(256), 0, stream>>>(fa);
  } else {
    // fallback: round-2 reg-staged path (64 MB scratch)
    GArgs pa;
    pa.A[0] = q; pa.W[0] = Wq;  pa.bias[0] = bq;  pa.C[0] = q1b; pa.oscale[0] = 0.125f; pa.vtrans[0] = 0;
    pa.A[1] = k; pa.W[1] = Wk;  pa.bias[1] = bk;  pa.C[1] = k1b; pa.oscale[1] = 1.0f;   pa.vtrans[1] = 0;
    pa.A[2] = v; pa.W[2] = Wv;  pa.bias[2] = bv;  pa.C[2] = vt1; pa.oscale[2] = 1.0f;   pa.vtrans[2] = 1;
    pa.A[3] = k; pa.W[3] = Wq2; pa.bias[3] = bq2; pa.C[3] = q2b; pa.oscale[3] = 0.125f; pa.vtrans[3] = 0;
    pa.A[4] = q; pa.W[4] = Wk2; pa.bias[4] = bk2; pa.C[4] = k2b; pa.oscale[4] = 1.0f;   pa.vtrans[4] = 0;
    pa.A[5] = q; pa.W[5] = Wv2; pa.bias[5] = bv2; pa.C[5] = vt2; pa.oscale[5] = 1.0f;   pa.vtrans[5] = 1;
    gemm_bt_batched<float, u16><<<dim3(8, 32, 6), dim3(256), 0, stream>>>(pa);

    attn_fused<<<dim3(8, 16, 8), dim3(512), 0, stream>>>(q1b, k1b, vt1, q2b, k2b, vt2, a1, a2);

    GArgs fa;
    fa.A[0] = a1; fa.W[0] = Wc;  fa.bias[0] = bc;  fa.C[0] = (float*)d_out;      fa.oscale[0] = 1.0f; fa.vtrans[0] = 0;
    fa.A[1] = a2; fa.W[1] = Wc2; fa.bias[1] = bc2; fa.C[1] = (float*)d_out + SZ; fa.oscale[1] = 1.0f; fa.vtrans[1] = 0;
    gemm_bt_batched<u16, float><<<dim3(8, 32, 2), dim3(256), 0, stream>>>(fa);
  }
}